// Round 7
// baseline (678459.619 us; speedup 1.0000x reference)
//
#include <hip/hip_runtime.h>

typedef __attribute__((ext_vector_type(8))) short short8;
typedef __attribute__((ext_vector_type(4))) float f32x4;
typedef __attribute__((ext_vector_type(4))) unsigned int u32x4;

#define TT 512
#define HD 1024
#define BD 64
#define NWG 256

union FRAG { u32x4 d; short8 s; };

// ---- fp32 -> bf16 round-to-nearest-even ----
__device__ __forceinline__ unsigned short f2bf(float f) {
  unsigned u = __float_as_uint(f);
  u += 0x7fffu + ((u >> 16) & 1u);
  return (unsigned short)(u >> 16);
}

__device__ __forceinline__ short8 ld_bf8(const float* s) {
  const f32x4* s4 = (const f32x4*)s;
  f32x4 lo = s4[0], hi = s4[1];
  short8 o;
#pragma unroll
  for (int j = 0; j < 4; ++j) {
    o[j] = (short)f2bf(lo[j]);
    o[4 + j] = (short)f2bf(hi[j]);
  }
  return o;
}

// ============================================================================
// Prep: inputs [B][T][512] fp32 -> XT bf16, A-fragment order, 8-row groups.
// XT[g(8)][t(512)][ks(16)][q(4)][m(8)] short8 ; g = b>>3, m = b&7.
// ============================================================================
__global__ void prep_xt(const float* __restrict__ x, short8* __restrict__ XT) {
  const int bid = blockIdx.x;  // b*512 + t
  const int b = bid >> 9;
  const int t = bid & 511;
  const int tid = threadIdx.x;  // k-octet
  const float* src = x + ((size_t)(b * TT + t)) * 512 + tid * 8;
  short8 o = ld_bf8(src);
  const int g = b >> 3, m = b & 7, ks = tid >> 2, q = tid & 3;
  XT[(((size_t)g * TT + t) * 16 + ks) * 32 + q * 8 + m] = o;
}

// h-state: per group: [parity(2)][ks(32)][line(64)][16B]; odd lines 8-15 etc
// (rows 8-15 of the MFMA tile) stay zero forever.
#define HFPAR ((size_t)32768)

// One flag-poll round: load + wait in ONE asm block (rule-18-safe; value is
// an SSA output so no consumer can be hoisted before the wait).
#define FLAGRD(SC)                                                        \
  asm volatile("global_load_dword %0, %1, off " SC "\n\t"                 \
               "s_waitcnt vmcnt(0)"                                       \
               : "=v"(fv) : "v"(hint_p) : "memory")

// The 8x16B h-fragment load, loads + single wait in ONE asm block.
#define LOADH8(SC)                                                        \
  asm volatile(                                                           \
      "global_load_dwordx4 %0, %8, off " SC "\n\t"                        \
      "global_load_dwordx4 %1, %8, off offset:1024 " SC "\n\t"            \
      "global_load_dwordx4 %2, %8, off offset:2048 " SC "\n\t"            \
      "global_load_dwordx4 %3, %8, off offset:3072 " SC "\n\t"            \
      "global_load_dwordx4 %4, %9, off " SC "\n\t"                        \
      "global_load_dwordx4 %5, %9, off offset:1024 " SC "\n\t"            \
      "global_load_dwordx4 %6, %9, off offset:2048 " SC "\n\t"            \
      "global_load_dwordx4 %7, %9, off offset:3072 " SC "\n\t"            \
      "s_waitcnt vmcnt(0)"                                                \
      : "=&v"(H[0]), "=&v"(H[1]), "=&v"(H[2]), "=&v"(H[3]),               \
        "=&v"(H[4]), "=&v"(H[5]), "=&v"(H[6]), "=&v"(H[7])                \
      : "v"(p0), "v"(p1)                                                  \
      : "memory")

#define ST4(P, V, SC)                                                     \
  asm volatile("global_store_dword %0, %1, off " SC ::"v"(P), "v"(V)      \
               : "memory")

// ============================================================================
// The scan body, templated on coherence domain:
//   LOCAL=true : group == physical XCD, all handoff ops sc0-only (coherent
//                at this XCD's L2, ~3x lower hop latency than LLC).
//   LOCAL=false: logical groups (blockIdx), sc0 sc1 (LLC) -- R5 semantics.
// Protocol (R5-proven): paired 4B h stores -> vmcnt(0) ack -> per-wave flag;
// consumer wave polls the 32 flags of exactly its 8 producer WGs, then does
// the 8x16B h load once. Buffer-reuse induction: the WG's 4 waves jointly
// cover all 32 producer WGs; two in-WG barriers merge that knowledge before
// any h_{t+1} store. All spins watchdogged: on pathological loss of progress
// the kernel TERMINATES with wrong output (visible) instead of hanging.
// MFMA geometry: 8 real batch rows of 16 (rows 8-15 dup/zero, discarded);
// 32 channels/WG = tile0 (LDS weights) + tile1 (VGPR weights).
// ============================================================================
template <bool LOCAL>
__device__ __forceinline__ void gru_scan(
    const float* Wxr, const float* bxr, const float* Whr,
    const float* Wxz, const float* bxz, const float* Whz,
    const float* Wxn, const float* bxn, const float* Whn,
    const short8* XT, char* HFc, unsigned* flags, float* out,
    char* lds, const int g, const int r, const int tid) {
  short8* wh = (short8*)lds;             // [3][32][64] (channel tile0)
  short8* wx = (short8*)(lds + 98304);   // [3][16][64] (channel tile0)
  float* red = (float*)(lds + 147456);   // [4 type][2 ctile][4 wv][32] f32x4

  const int wv = tid >> 6;
  const int lane = tid & 63;
  const int c0 = r << 5;   // 32 channels [c0, c0+32)
  const int n1 = c0 + 16;  // channel tile1 base

  // ---- stage tile0 Wh (B-fragment order) into LDS
  for (int idx = tid; idx < 3 * 32 * 64; idx += 256) {
    const int g3 = idx >> 11, rem = idx & 2047, ks = rem >> 6, ln = rem & 63;
    const float* W = (g3 == 0) ? Whr : (g3 == 1) ? Whz : Whn;
    wh[idx] = ld_bf8(W + (size_t)(c0 + (ln & 15)) * HD + ks * 32 + (ln >> 4) * 8);
  }
  // ---- stage tile0 Wx into LDS
  for (int idx = tid; idx < 3 * 16 * 64; idx += 256) {
    const int g3 = idx >> 10, rem = idx & 1023, ks = rem >> 6, ln = rem & 63;
    const float* W = (g3 == 0) ? Wxr : (g3 == 1) ? Wxz : Wxn;
    wx[idx] = ld_bf8(W + (size_t)(c0 + (ln & 15)) * 512 + ks * 32 + (ln >> 4) * 8);
  }
  // ---- stage tile1 weights into VGPRs (loop-invariant)
  short8 wh1r[8], wh1z[8], wh1n[8], wx1r[4], wx1z[4], wx1n[4];
  {
    const size_t bc = (size_t)(n1 + (lane & 15));
    const int ko = (lane >> 4) * 8;
#pragma unroll
    for (int kk = 0; kk < 8; ++kk) {
      const int ks = (wv << 3) + kk;
      wh1r[kk] = ld_bf8(Whr + bc * HD + ks * 32 + ko);
      wh1z[kk] = ld_bf8(Whz + bc * HD + ks * 32 + ko);
      wh1n[kk] = ld_bf8(Whn + bc * HD + ks * 32 + ko);
    }
#pragma unroll
    for (int kk = 0; kk < 4; ++kk) {
      const int ks = (wv << 2) + kk;
      wx1r[kk] = ld_bf8(Wxr + bc * 512 + ks * 32 + ko);
      wx1z[kk] = ld_bf8(Wxz + bc * 512 + ks * 32 + ko);
      wx1n[kk] = ld_bf8(Wxn + bc * 512 + ks * 32 + ko);
    }
  }
  __syncthreads();

  // ---- per-thread output ownership: 8 b x 32 c per WG, 1 cell/thread
  const int c_off = tid & 31, b_off = tid >> 5;  // b_off in [0,8)
  const int c = c0 + c_off;
  const int b = (g << 3) + b_off;
  const float br_ = bxr[c], bz_ = bxz[c], bn_ = bxn[c];
  float h_old = 0.f;

  const int ct = c_off >> 4;                          // this thread's c-tile
  const int sl = ((b_off >> 2) << 4) + (c_off & 15);  // source lane (<32)
  const int rg = b_off & 3;                           // source reg

  // producer: even-c_off threads store the (c,c+1) dword; line slot == r
  char* HFg = HFc + (size_t)g * 2 * HFPAR;
  const size_t prod_off =
      ((size_t)(r * 64 + (c_off >> 3) * 16 + b_off)) * 16 +
      (size_t)(c_off & 7) * 2;
  unsigned* flag_g = flags + g * 128;
  unsigned* my_flag = flag_g + r * 4 + wv;
  // consumer: wave wv loads ks slots [wv*8, wv*8+8) == producer WGs r' in
  // that range -> poll exactly their 32 (WG,wave) flags (2 lanes per flag)
  const unsigned* hint_p = flag_g + (wv << 5) + (lane & 31);
  const char* cons_base = HFg + (size_t)(wv << 3) * 1024 + (size_t)lane * 16;

  float* out_hlast = out;
  float* out_hidden = out + BD * HD;

  const int qx = lane >> 4, mrx = lane & 7;  // x A-frag: rows 8-15 duplicate

  for (int t = 0; t < TT; ++t) {
    const char* cb = cons_base + (size_t)(t & 1) * HFPAR;
    const char* p0 = cb;
    const char* p1 = cb + 4096;

    // ---- x A-frags
    const short8* xb = XT + (((size_t)g * TT + t) * 16) * 32;
    short8 xa[4];
#pragma unroll
    for (int kk = 0; kk < 4; ++kk)
      xa[kk] = xb[((wv << 2) + kk) * 32 + qx * 8 + mrx];

    f32x4 aR0 = {0.f, 0.f, 0.f, 0.f}, aZ0 = aR0, aNh0 = aR0, aNx0 = aR0;
    f32x4 aR1 = aR0, aZ1 = aR0, aNh1 = aR0, aNx1 = aR0;

    // ---- x MFMAs (tile0 from LDS, tile1 from regs)
#pragma unroll
    for (int kk = 0; kk < 4; ++kk) {
      const int ks = (wv << 2) + kk;
      aR0 = __builtin_amdgcn_mfma_f32_16x16x32_bf16(xa[kk], wx[(0 * 16 + ks) * 64 + lane], aR0, 0, 0, 0);
      aZ0 = __builtin_amdgcn_mfma_f32_16x16x32_bf16(xa[kk], wx[(1 * 16 + ks) * 64 + lane], aZ0, 0, 0, 0);
      aNx0 = __builtin_amdgcn_mfma_f32_16x16x32_bf16(xa[kk], wx[(2 * 16 + ks) * 64 + lane], aNx0, 0, 0, 0);
      aR1 = __builtin_amdgcn_mfma_f32_16x16x32_bf16(xa[kk], wx1r[kk], aR1, 0, 0, 0);
      aZ1 = __builtin_amdgcn_mfma_f32_16x16x32_bf16(xa[kk], wx1z[kk], aZ1, 0, 0, 0);
      aNx1 = __builtin_amdgcn_mfma_f32_16x16x32_bf16(xa[kk], wx1n[kk], aNx1, 0, 0, 0);
    }

    // ---- flag spin (self-paced rounds, watchdogged) then one-shot h load
    {
      const unsigned tt_ = (unsigned)t;
      unsigned fv;
      if constexpr (LOCAL) { FLAGRD("sc0"); } else { FLAGRD("sc0 sc1"); }
      int spins = 0;
      while (!__all((int)(fv >= tt_))) {
        if (++spins > 16384) break;  // terminate visibly, never hang
        if (spins > 8) __builtin_amdgcn_s_sleep(1);
        if constexpr (LOCAL) { FLAGRD("sc0"); } else { FLAGRD("sc0 sc1"); }
      }
    }
    u32x4 H[8];
    if constexpr (LOCAL) { LOADH8("sc0"); } else { LOADH8("sc0 sc1"); }

    // ---- h MFMAs
#pragma unroll
    for (int kk = 0; kk < 8; ++kk) {
      FRAG f;
      f.d = H[kk];
      const int ks = (wv << 3) + kk;
      aR0 = __builtin_amdgcn_mfma_f32_16x16x32_bf16(f.s, wh[(0 * 32 + ks) * 64 + lane], aR0, 0, 0, 0);
      aZ0 = __builtin_amdgcn_mfma_f32_16x16x32_bf16(f.s, wh[(1 * 32 + ks) * 64 + lane], aZ0, 0, 0, 0);
      aNh0 = __builtin_amdgcn_mfma_f32_16x16x32_bf16(f.s, wh[(2 * 32 + ks) * 64 + lane], aNh0, 0, 0, 0);
      aR1 = __builtin_amdgcn_mfma_f32_16x16x32_bf16(f.s, wh1r[kk], aR1, 0, 0, 0);
      aZ1 = __builtin_amdgcn_mfma_f32_16x16x32_bf16(f.s, wh1z[kk], aZ1, 0, 0, 0);
      aNh1 = __builtin_amdgcn_mfma_f32_16x16x32_bf16(f.s, wh1n[kk], aNh1, 0, 0, 0);
    }

    // ---- cross-wave K-reduction (only rows 0-7 real -> writer lanes < 32)
    {
      f32x4* r4 = (f32x4*)red;
      if (lane < 32) {
        r4[((0 * 2 + 0) * 4 + wv) * 32 + lane] = aR0;
        r4[((0 * 2 + 1) * 4 + wv) * 32 + lane] = aR1;
        r4[((1 * 2 + 0) * 4 + wv) * 32 + lane] = aZ0;
        r4[((1 * 2 + 1) * 4 + wv) * 32 + lane] = aZ1;
        r4[((2 * 2 + 0) * 4 + wv) * 32 + lane] = aNh0;
        r4[((2 * 2 + 1) * 4 + wv) * 32 + lane] = aNh1;
        r4[((3 * 2 + 0) * 4 + wv) * 32 + lane] = aNx0;
        r4[((3 * 2 + 1) * 4 + wv) * 32 + lane] = aNx1;
      }
    }
    __syncthreads();
    float sR = 0.f, sZ = 0.f, sNh = 0.f, sNx = 0.f;
#pragma unroll
    for (int v = 0; v < 4; ++v) {
      sR += red[(((0 * 2 + ct) * 4 + v) * 32 + sl) * 4 + rg];
      sZ += red[(((1 * 2 + ct) * 4 + v) * 32 + sl) * 4 + rg];
      sNh += red[(((2 * 2 + ct) * 4 + v) * 32 + sl) * 4 + rg];
      sNx += red[(((3 * 2 + ct) * 4 + v) * 32 + sl) * 4 + rg];
    }
    __syncthreads();  // red rewritten next iter; also merges flag knowledge

    // ---- gates
    const float rr_ = 1.f / (1.f + __expf(-(sR + br_)));
    const float z = 1.f / (1.f + __expf(-(sZ + bz_)));
    float pre_n = sNx + bn_ + rr_ * sNh;
    pre_n = fminf(fmaxf(pre_n, -30.f), 30.f);
    const float e2 = __expf(2.f * pre_n);
    const float n = (e2 - 1.f) / (e2 + 1.f);
    const float hn = (1.f - z) * n + z * h_old;
    h_old = hn;

    // ---- paired h store -> vmcnt(0) ack -> per-wave flag (R5 semantics)
    const unsigned hb = f2bf(hn);
    const unsigned hb_hi = (unsigned)__shfl_down((int)hb, 1);

    if (t < TT - 1) {
      if (!(c_off & 1)) {
        char* dst = HFg + (size_t)((t + 1) & 1) * HFPAR + prod_off;
        const unsigned val = hb | (hb_hi << 16);
        if constexpr (LOCAL) { ST4(dst, val, "sc0"); }
        else { ST4(dst, val, "sc0 sc1"); }
      }
      asm volatile("s_waitcnt vmcnt(0)" ::: "memory");  // data acked
      if (lane == 0) {
        const unsigned fvv = (unsigned)(t + 1);
        if constexpr (LOCAL) { ST4(my_flag, fvv, "sc0"); }
        else { ST4(my_flag, fvv, "sc0 sc1"); }
      }
      out_hidden[((size_t)b * TT + t) * HD + c] = hn;
    } else {
      out_hidden[((size_t)b * TT + t) * HD + c] = hn;
      out_hlast[(size_t)b * HD + c] = hn;
    }
  }
}

// ============================================================================
// 256 WGs x 160KB LDS -> 1 WG/CU. Census prologue: each WG claims a ticket
// on its PHYSICAL XCD; grid-wide done-counter (co-residency is already
// load-bearing in every passing round); if all 8 XCDs hold exactly 32 WGs,
// take the intra-XCD sc0 path with (xcd, ticket); else fall back to logical
// (blockIdx) groups at LLC scope. Decision is made from post-census state,
// so all WGs that see done==256 agree.
// ============================================================================
__global__ __launch_bounds__(256, 1) void gru_main(
    const float* __restrict__ Wxr, const float* __restrict__ bxr,
    const float* __restrict__ Whr,
    const float* __restrict__ Wxz, const float* __restrict__ bxz,
    const float* __restrict__ Whz,
    const float* __restrict__ Wxn, const float* __restrict__ bxn,
    const float* __restrict__ Whn,
    const short8* __restrict__ XT, char* __restrict__ HFc,
    unsigned* __restrict__ flags, int* __restrict__ cnt,
    int* __restrict__ done, float* __restrict__ out) {
  extern __shared__ char lds[];
  const int tid = threadIdx.x;

  unsigned xcc;
  asm volatile("s_getreg_b32 %0, hwreg(HW_REG_XCC_ID)" : "=s"(xcc));
  const int gp = (int)(xcc & 7);

  volatile int* sh = (volatile int*)lds;
  if (tid == 0) {
    const int tk = atomicAdd(cnt + gp, 1);
    __threadfence();
    atomicAdd(done, 1);
    int d = 0;
    long it = 0;
    do {
      d = __hip_atomic_load(done, __ATOMIC_RELAXED, __HIP_MEMORY_SCOPE_AGENT);
      if (++it > (1 << 24)) break;  // watchdog: decide fallback, don't hang
    } while (d < NWG);
    __threadfence();
    int bal = (d >= NWG);
    for (int x = 0; x < 8; ++x)
      bal &= (__hip_atomic_load(cnt + x, __ATOMIC_RELAXED,
                                __HIP_MEMORY_SCOPE_AGENT) == 32);
    sh[0] = tk;
    sh[1] = bal;
  }
  __syncthreads();
  const int ticket = sh[0];
  const int balanced = sh[1];
  __syncthreads();

  if (balanced) {
    gru_scan<true>(Wxr, bxr, Whr, Wxz, bxz, Whz, Wxn, bxn, Whn, XT, HFc,
                   flags, out, lds, gp, ticket, tid);
  } else {
    gru_scan<false>(Wxr, bxr, Whr, Wxz, bxz, Whz, Wxn, bxn, Whn, XT, HFc,
                    flags, out, lds, (int)(blockIdx.x & 7),
                    (int)(blockIdx.x >> 3), tid);
  }
}

// ============================================================================
extern "C" void kernel_launch(void* const* d_in, const int* in_sizes, int n_in,
                              void* d_out, int out_size, void* d_ws, size_t ws_size,
                              hipStream_t stream) {
  const float* inputs = (const float*)d_in[0];
  const float* Wxr = (const float*)d_in[1];
  const float* bxr = (const float*)d_in[2];
  const float* Whr = (const float*)d_in[3];
  const float* Wxz = (const float*)d_in[4];
  const float* bxz = (const float*)d_in[5];
  const float* Whz = (const float*)d_in[6];
  const float* Wxn = (const float*)d_in[7];
  const float* bxn = (const float*)d_in[8];
  const float* Whn = (const float*)d_in[9];
  float* out = (float*)d_out;

  char* ws = (char*)d_ws;
  short8* XT = (short8*)ws;                               // 33,554,432 B
  char* HF = ws + 33554432;                               //    524,288 B
  unsigned* flags = (unsigned*)(ws + 33554432 + 524288);  //      4,096 B
  int* cnt = (int*)(ws + 33554432 + 524288 + 4096);       //         32 B
  int* done = (int*)(ws + 33554432 + 524288 + 4096 + 32); //          4 B

  // h0 = 0 both parities (tile rows 8-15 stay zero forever); flags = 0
  // (t=0 check 0>=0 passes); census counters re-zeroed every launch.
  hipMemsetAsync(HF, 0, 524288 + 4096 + 64, stream);
  prep_xt<<<dim3(64 * 512), dim3(64), 0, stream>>>(inputs, XT);

  (void)hipFuncSetAttribute((const void*)gru_main,
                            hipFuncAttributeMaxDynamicSharedMemorySize, 163840);
  gru_main<<<dim3(NWG), dim3(256), 163840, stream>>>(
      Wxr, bxr, Whr, Wxz, bxz, Whz, Wxn, bxn, Whn, XT, HF, flags, cnt, done,
      out);
}

// Round 8
// 1955.280 us; speedup vs baseline: 346.9885x; 346.9885x over previous
//
#include <hip/hip_runtime.h>

typedef __attribute__((ext_vector_type(8))) short short8;
typedef __attribute__((ext_vector_type(4))) float f32x4;
typedef __attribute__((ext_vector_type(4))) unsigned int u32x4;

#define TT 512
#define HD 1024
#define BD 64
#define NWG 256

union FRAG { u32x4 d; short8 s; };

// ---- fp32 -> bf16 round-to-nearest-even ----
__device__ __forceinline__ unsigned short f2bf(float f) {
  unsigned u = __float_as_uint(f);
  u += 0x7fffu + ((u >> 16) & 1u);
  return (unsigned short)(u >> 16);
}

__device__ __forceinline__ short8 ld_bf8(const float* s) {
  const f32x4* s4 = (const f32x4*)s;
  f32x4 lo = s4[0], hi = s4[1];
  short8 o;
#pragma unroll
  for (int j = 0; j < 4; ++j) {
    o[j] = (short)f2bf(lo[j]);
    o[4 + j] = (short)f2bf(hi[j]);
  }
  return o;
}

// ============================================================================
// Prep: inputs [B][T][512] fp32 -> XT bf16 in MFMA A-fragment order (R5).
// ============================================================================
__global__ void prep_xt(const float* __restrict__ x, short8* __restrict__ XT) {
  const int bid = blockIdx.x;  // b*512 + t
  const int b = bid >> 9;
  const int t = bid & 511;
  const int tid = threadIdx.x;  // k-octet
  short8 o = ld_bf8(x + ((size_t)(b * TT + t)) * 512 + tid * 8);
  const int bt = b >> 4, m = b & 15, ks = tid >> 2, q = tid & 3;
  XT[(((size_t)bt * TT + t) * 16 + ks) * 64 + q * 16 + m] = o;
}

// h-state: 2 parities x [4 bt][32 ks][64 lane][16B] = 2 x 131072 B
#define PARB ((size_t)131072)

// R5-proven wait-and-load, ONE asm block (rule-18-safe): 2-deep pipelined
// spin on this wave's 64 producer flags (1 dword/lane), then immediately the
// 8x16B h loads; single vmcnt(0) drains stale flag loads under data flight.
#define WAIT_AND_LOAD()                                                   \
  asm volatile(                                                           \
      "global_load_dword %8, %10, off sc0 sc1\n\t"                        \
      "s_sleep 4\n\t"                                                     \
      "global_load_dword %9, %10, off sc0 sc1\n\t"                        \
      "1:\n\t"                                                            \
      "s_waitcnt vmcnt(1)\n\t"                                            \
      "v_cmp_gt_u32 vcc, %11, %8\n\t"                                     \
      "s_cbranch_vccz 2f\n\t"                                             \
      "global_load_dword %8, %10, off sc0 sc1\n\t"                        \
      "s_waitcnt vmcnt(1)\n\t"                                            \
      "v_cmp_gt_u32 vcc, %11, %9\n\t"                                     \
      "s_cbranch_vccz 2f\n\t"                                             \
      "global_load_dword %9, %10, off sc0 sc1\n\t"                        \
      "s_branch 1b\n\t"                                                   \
      "2:\n\t"                                                            \
      "global_load_dwordx4 %0, %12, off sc0 sc1\n\t"                      \
      "global_load_dwordx4 %1, %12, off offset:1024 sc0 sc1\n\t"          \
      "global_load_dwordx4 %2, %12, off offset:2048 sc0 sc1\n\t"          \
      "global_load_dwordx4 %3, %12, off offset:3072 sc0 sc1\n\t"          \
      "global_load_dwordx4 %4, %13, off sc0 sc1\n\t"                      \
      "global_load_dwordx4 %5, %13, off offset:1024 sc0 sc1\n\t"          \
      "global_load_dwordx4 %6, %13, off offset:2048 sc0 sc1\n\t"          \
      "global_load_dwordx4 %7, %13, off offset:3072 sc0 sc1\n\t"          \
      "s_waitcnt vmcnt(0)"                                                \
      : "=&v"(H[0]), "=&v"(H[1]), "=&v"(H[2]), "=&v"(H[3]),               \
        "=&v"(H[4]), "=&v"(H[5]), "=&v"(H[6]), "=&v"(H[7]),               \
        "=&v"(f0s), "=&v"(f1s)                                            \
      : "v"(hint_p), "v"(tt_), "v"(p0), "v"(p1)                           \
      : "vcc", "memory")

// ============================================================================
// Persistent fused GRU scan. 256 WGs = 4 groups (bt) x 64 (ct). Protocol is
// VERBATIM R5 (measured best, 1347us): paired 4B h stores -> vmcnt(0) ack ->
// per-wave flag (all sc0 sc1 / LLC — R7 proved sc0-only visibility broken);
// consumer wave spins on its 16 producer WGs' 64 flags merged with the
// 8x16B h load in one asm block. Safety induction unchanged (4 waves jointly
// cover all 64 producer WGs; barrier merges that before any h_{t+1} store).
//
// R8 deltas (compute-chain trims, protocol untouched):
//   1. ALL weights permanently in VGPRs (36 short8/thread = 144 VGPR) —
//      removes 36 ds_read_b128/step from the critical path (reg-staged
//      weight correctness proven by R7's passing run).
//   2. LDS = reduction buffer only, DOUBLE-BUFFERED by step parity ->
//      second __syncthreads dropped (writer of red[p] at t+2 passed
//      barrier-1 of t+1, which required all waves' step-t reads done).
//   3. LDS request padded to 96KB -> exactly 1 WG/CU (co-residency that
//      the spin protocol relies on is preserved by construction).
// ============================================================================
__global__ __launch_bounds__(256, 1) void gru_main(
    const float* __restrict__ Wxr, const float* __restrict__ bxr,
    const float* __restrict__ Whr,
    const float* __restrict__ Wxz, const float* __restrict__ bxz,
    const float* __restrict__ Whz,
    const float* __restrict__ Wxn, const float* __restrict__ bxn,
    const float* __restrict__ Whn,
    const short8* __restrict__ XT, char* __restrict__ HFc,
    unsigned* __restrict__ flags, float* __restrict__ out) {
  extern __shared__ char lds[];
  float* red = (float*)lds;  // [2 parity][4 type][4 wv][64 lane] f32x4

  const int wg = blockIdx.x;
  const int bt = wg & 3;   // batch group
  const int ct = wg >> 2;  // 0..63 group member
  const int c0 = ct << 4;
  const int tid = threadIdx.x;
  const int wv = tid >> 6;
  const int lane = tid & 63;

  // ---- permanent per-thread weight fragments (B-frag order, R6/R7-proven
  // mapping): col = c0 + (lane&15), k-octet = ks*32 + (lane>>4)*8
  short8 whr_[8], whz_[8], whn_[8], wxr_[4], wxz_[4], wxn_[4];
  {
    const size_t bc = (size_t)(c0 + (lane & 15));
    const int ko = (lane >> 4) * 8;
#pragma unroll
    for (int kk = 0; kk < 8; ++kk) {
      const int ks = (wv << 3) + kk;
      whr_[kk] = ld_bf8(Whr + bc * HD + ks * 32 + ko);
      whz_[kk] = ld_bf8(Whz + bc * HD + ks * 32 + ko);
      whn_[kk] = ld_bf8(Whn + bc * HD + ks * 32 + ko);
    }
#pragma unroll
    for (int kk = 0; kk < 4; ++kk) {
      const int ks = (wv << 2) + kk;
      wxr_[kk] = ld_bf8(Wxr + bc * 512 + ks * 32 + ko);
      wxz_[kk] = ld_bf8(Wxz + bc * 512 + ks * 32 + ko);
      wxn_[kk] = ld_bf8(Wxn + bc * 512 + ks * 32 + ko);
    }
  }

  // ---- per-thread output ownership (R5)
  const int c_off = tid & 15, b_off = tid >> 4;
  const int c = c0 + c_off;
  const int b = (bt << 4) + b_off;
  const float br_ = bxr[c], bz_ = bxz[c], bn_ = bxn[c];
  float h_old = 0.f;

  const int rl = ((b_off >> 2) << 4) + c_off;
  const int rr = b_off & 3;

  // producer h byte offset (even-c threads store the (c,c+1) dword pair)
  const size_t prod_byte =
      ((size_t)((bt * 32 + (c >> 5)) * 64 + ((c >> 3) & 3) * 16 + b_off)) * 16 +
      (size_t)(c & 7) * 2;
  unsigned* my_flag = flags + bt * 256 + ct * 4 + wv;
  const unsigned* hint_p = flags + bt * 256 + (wv << 6) + lane;
  const char* cons_base =
      HFc + ((size_t)(bt * 32 + (wv << 3)) * 64 + lane) * 16;

  float* out_hlast = out;
  float* out_hidden = out + BD * HD;

  for (int t = 0; t < TT; ++t) {
    const char* cb = cons_base + (size_t)(t & 1) * PARB;
    const char* p0 = cb;
    const char* p1 = cb + 4096;

    // ---- x fragments + x MFMAs (weights from regs; independent of h_t)
    const short8* xrd = XT + (((size_t)bt * TT + t) * 16 + (wv << 2)) * 64 + lane;
    short8 xa[4];
#pragma unroll
    for (int kk = 0; kk < 4; ++kk) xa[kk] = xrd[kk * 64];

    f32x4 aR = {0.f, 0.f, 0.f, 0.f};
    f32x4 aZ = {0.f, 0.f, 0.f, 0.f};
    f32x4 aNh = {0.f, 0.f, 0.f, 0.f};
    f32x4 aNx = {0.f, 0.f, 0.f, 0.f};
#pragma unroll
    for (int kk = 0; kk < 4; ++kk) {
      aR = __builtin_amdgcn_mfma_f32_16x16x32_bf16(xa[kk], wxr_[kk], aR, 0, 0, 0);
      aZ = __builtin_amdgcn_mfma_f32_16x16x32_bf16(xa[kk], wxz_[kk], aZ, 0, 0, 0);
      aNx = __builtin_amdgcn_mfma_f32_16x16x32_bf16(xa[kk], wxn_[kk], aNx, 0, 0, 0);
    }

    // ---- per-wave narrowed wait + h load (R5-proven asm block)
    u32x4 H[8];
    unsigned f0s, f1s;
    const unsigned tt_ = (unsigned)t;
    WAIT_AND_LOAD();

    // ---- h MFMAs: A-frags straight from asm outputs, B-frags from regs
#pragma unroll
    for (int kk = 0; kk < 8; ++kk) {
      FRAG f;
      f.d = H[kk];
      aR = __builtin_amdgcn_mfma_f32_16x16x32_bf16(f.s, whr_[kk], aR, 0, 0, 0);
      aZ = __builtin_amdgcn_mfma_f32_16x16x32_bf16(f.s, whz_[kk], aZ, 0, 0, 0);
      aNh = __builtin_amdgcn_mfma_f32_16x16x32_bf16(f.s, whn_[kk], aNh, 0, 0, 0);
    }

    // ---- single-round cross-wave K-reduction, parity double-buffered,
    // ONE barrier (see header for the safety derivation)
    float* redb = red + (t & 1) * (4 * 4 * 64 * 4);
    {
      f32x4* r4 = (f32x4*)redb;
      r4[(0 * 4 + wv) * 64 + lane] = aR;
      r4[(1 * 4 + wv) * 64 + lane] = aZ;
      r4[(2 * 4 + wv) * 64 + lane] = aNh;
      r4[(3 * 4 + wv) * 64 + lane] = aNx;
    }
    __syncthreads();
    float sR = 0.f, sZ = 0.f, sNh = 0.f, sNx = 0.f;
#pragma unroll
    for (int v = 0; v < 4; ++v) {
      sR += redb[((0 * 4 + v) * 64 + rl) * 4 + rr];
      sZ += redb[((1 * 4 + v) * 64 + rl) * 4 + rr];
      sNh += redb[((2 * 4 + v) * 64 + rl) * 4 + rr];
      sNx += redb[((3 * 4 + v) * 64 + rl) * 4 + rr];
    }

    // ---- gates
    const float r = 1.f / (1.f + __expf(-(sR + br_)));
    const float z = 1.f / (1.f + __expf(-(sZ + bz_)));
    float pre_n = sNx + bn_ + r * sNh;
    pre_n = fminf(fmaxf(pre_n, -30.f), 30.f);
    const float e2 = __expf(2.f * pre_n);
    const float n = (e2 - 1.f) / (e2 + 1.f);
    const float hn = (1.f - z) * n + z * h_old;
    h_old = hn;

    // ---- paired h store (4B), vmcnt(0) ack, then flag (R5 semantics)
    const unsigned hb = f2bf(hn);
    const unsigned hb_hi = (unsigned)__shfl_down((int)hb, 1);

    if (t < TT - 1) {
      if (!(c_off & 1)) {
        __hip_atomic_store(
            (unsigned*)(HFc + (size_t)((t + 1) & 1) * PARB + prod_byte),
            hb | (hb_hi << 16), __ATOMIC_RELAXED, __HIP_MEMORY_SCOPE_AGENT);
      }
      asm volatile("s_waitcnt vmcnt(0)" ::: "memory");  // data acked at LLC
      if (lane == 0) {
        __hip_atomic_store(my_flag, (unsigned)(t + 1), __ATOMIC_RELAXED,
                           __HIP_MEMORY_SCOPE_AGENT);
      }
      // out store drains under the next step (off the critical path)
      out_hidden[((size_t)b * TT + t) * HD + c] = hn;
    } else {
      out_hidden[((size_t)b * TT + t) * HD + c] = hn;
      out_hlast[(size_t)b * HD + c] = hn;
    }
  }
}

// ============================================================================
extern "C" void kernel_launch(void* const* d_in, const int* in_sizes, int n_in,
                              void* d_out, int out_size, void* d_ws, size_t ws_size,
                              hipStream_t stream) {
  const float* inputs = (const float*)d_in[0];
  const float* Wxr = (const float*)d_in[1];
  const float* bxr = (const float*)d_in[2];
  const float* Whr = (const float*)d_in[3];
  const float* Wxz = (const float*)d_in[4];
  const float* bxz = (const float*)d_in[5];
  const float* Whz = (const float*)d_in[6];
  const float* Wxn = (const float*)d_in[7];
  const float* bxn = (const float*)d_in[8];
  const float* Whn = (const float*)d_in[9];
  float* out = (float*)d_out;

  char* ws = (char*)d_ws;
  short8* XT = (short8*)ws;                              // 33,554,432 B
  char* HF = ws + 33554432;                              //    262,144 B
  unsigned* flags = (unsigned*)(ws + 33554432 + 262144); //      4,096 B

  // h0 = 0 (both parities) + flags = 0 (t=0 check: 0 > 0 false -> pass).
  hipMemsetAsync(HF, 0, 262144 + 4096, stream);
  prep_xt<<<dim3(64 * 512), dim3(64), 0, stream>>>(inputs, XT);

  // 96KB dynamic LDS: red uses 32KB; padding pins occupancy to 1 WG/CU so
  // the spin protocol's co-residency assumption holds by construction.
  (void)hipFuncSetAttribute((const void*)gru_main,
                            hipFuncAttributeMaxDynamicSharedMemorySize, 98304);
  gru_main<<<dim3(NWG), dim3(256), 98304, stream>>>(
      Wxr, bxr, Whr, Wxz, bxz, Whz, Wxn, bxn, Whn, XT, HF, flags, out);
}